// Round 1
// baseline (6196.909 us; speedup 1.0000x reference)
//
#include <hip/hip_runtime.h>
#include <math.h>

#define HD 64   // H == F == 64
#define GD 50   // num gaussians

__device__ __forceinline__ float ssp_f(float x) {
    // shifted softplus: log1p(exp(x)) - ln(2); inputs here are small (|x| < ~10)
    float sp = (x > 15.0f) ? x : log1pf(__expf(x));
    return sp - 0.69314718055994531f;
}

// xs = x @ l1w : [N,64] = [N,64] @ [64,64]. One wave per node, lane = out col.
__global__ void __launch_bounds__(256) xs_kernel(const float* __restrict__ x,
                                                 const float* __restrict__ w,
                                                 float* __restrict__ xs, int N) {
    int wv = threadIdx.x >> 6;
    int j  = threadIdx.x & 63;
    int n  = blockIdx.x * 4 + wv;
    __shared__ float xr[4][64];
    if (n < N) xr[wv][j] = x[(size_t)n * HD + j];
    __syncthreads();
    if (n >= N) return;
    float acc = 0.0f;
#pragma unroll
    for (int k = 0; k < HD; ++k)
        acc = fmaf(xr[wv][k], w[k * HD + j], acc);
    xs[(size_t)n * HD + j] = acc;
}

// Per-edge fused: filter MLP (G->F ssp F->F) * cosine cutoff, gather xs[src],
// modulate, scatter-add to agg[dst]. One thread per edge; h/w vectors in VGPRs,
// weight indices are loop constants -> scalar loads (s_load), FMA-issue bound.
__global__ void __launch_bounds__(128) edge_kernel(
        const float* __restrict__ ea, const float* __restrict__ ew,
        const int* __restrict__ ei, const float* __restrict__ xs,
        float* __restrict__ agg,
        const float* __restrict__ mw1, const float* __restrict__ mb1,
        const float* __restrict__ mw2, const float* __restrict__ mb2,
        int E) {
    int e = blockIdx.x * blockDim.x + threadIdx.x;
    if (e >= E) return;

    const float* ear = ea + (size_t)e * GD;

    float h[HD];
#pragma unroll
    for (int f = 0; f < HD; ++f) h[f] = mb1[f];

#pragma unroll 2
    for (int g = 0; g < GD; ++g) {
        float a = ear[g];
        const float* wr = mw1 + g * HD;
#pragma unroll
        for (int f = 0; f < HD; ++f) h[f] = fmaf(a, wr[f], h[f]);
    }

    float w[HD];
#pragma unroll
    for (int j = 0; j < HD; ++j) w[j] = mb2[j];

#pragma unroll
    for (int g = 0; g < HD; ++g) {
        float s = ssp_f(h[g]);
        const float* wr = mw2 + g * HD;
#pragma unroll
        for (int j = 0; j < HD; ++j) w[j] = fmaf(s, wr[j], w[j]);
    }

    // cosine cutoff on distance
    float cw = 0.5f * (__cosf(ew[e] * 0.31415926535897931f) + 1.0f);

    int src = ei[e];        // edge_index row 0
    int dst = ei[E + e];    // edge_index row 1
    const float* xr = xs + (size_t)src * HD;
    float* ar = agg + (size_t)dst * HD;
#pragma unroll
    for (int j = 0; j < HD; ++j)
        atomicAdd(&ar[j], xr[j] * w[j] * cw);
}

// out = ssp(agg @ l2w + l2b) @ lin_w + lin_b. One wave per node, LDS broadcast.
__global__ void __launch_bounds__(256) out_kernel(
        const float* __restrict__ agg,
        const float* __restrict__ l2w, const float* __restrict__ l2b,
        const float* __restrict__ lw, const float* __restrict__ lb,
        float* __restrict__ out, int N) {
    int wv = threadIdx.x >> 6;
    int j  = threadIdx.x & 63;
    int n  = blockIdx.x * 4 + wv;
    __shared__ float buf[4][64];
    bool ok = n < N;
    if (ok) buf[wv][j] = agg[(size_t)n * HD + j];
    __syncthreads();
    float h = l2b[j];
#pragma unroll
    for (int g = 0; g < HD; ++g)
        h = fmaf(buf[wv][g], l2w[g * HD + j], h);
    h = ssp_f(h);
    __syncthreads();          // all reads of buf done before overwrite
    buf[wv][j] = h;
    __syncthreads();
    float o = lb[j];
#pragma unroll
    for (int g = 0; g < HD; ++g)
        o = fmaf(buf[wv][g], lw[g * HD + j], o);
    if (ok) out[(size_t)n * HD + j] = o;
}

extern "C" void kernel_launch(void* const* d_in, const int* in_sizes, int n_in,
                              void* d_out, int out_size, void* d_ws, size_t ws_size,
                              hipStream_t stream) {
    const float* x0   = (const float*)d_in[0];
    const float* x1   = (const float*)d_in[1];
    const int*   ei0  = (const int*)d_in[2];
    const int*   ei1  = (const int*)d_in[3];
    const float* ew0  = (const float*)d_in[4];
    const float* ew1  = (const float*)d_in[5];
    const float* ea0  = (const float*)d_in[6];
    const float* ea1  = (const float*)d_in[7];
    const float* mw1  = (const float*)d_in[8];
    const float* mb1  = (const float*)d_in[9];
    const float* mw2  = (const float*)d_in[10];
    const float* mb2  = (const float*)d_in[11];
    const float* l1w0 = (const float*)d_in[12];
    const float* l2w0 = (const float*)d_in[13];
    const float* l2b0 = (const float*)d_in[14];
    const float* l1w1 = (const float*)d_in[15];
    const float* l2w1 = (const float*)d_in[16];
    const float* l2b1 = (const float*)d_in[17];
    const float* lw   = (const float*)d_in[18];
    const float* lb   = (const float*)d_in[19];

    int N = in_sizes[0] / HD;
    int E = in_sizes[4];
    float* out = (float*)d_out;

    // workspace: xs [N*64] then agg [N*64], reused across the two edge types
    float* xs  = (float*)d_ws;
    float* agg = xs + (size_t)N * HD;

    int nodeBlocks = (N + 3) / 4;
    int edgeBlocks = (E + 127) / 128;

    for (int t = 0; t < 2; ++t) {
        const float* x   = t ? x1 : x0;
        const int*   ei  = t ? ei1 : ei0;
        const float* ew  = t ? ew1 : ew0;
        const float* ea  = t ? ea1 : ea0;
        const float* l1w = t ? l1w1 : l1w0;
        const float* l2w = t ? l2w1 : l2w0;
        const float* l2b = t ? l2b1 : l2b0;
        float* outp = out + (size_t)t * (size_t)N * HD;

        xs_kernel<<<nodeBlocks, 256, 0, stream>>>(x, l1w, xs, N);
        hipMemsetAsync(agg, 0, (size_t)N * HD * sizeof(float), stream);
        edge_kernel<<<edgeBlocks, 128, 0, stream>>>(ea, ew, ei, xs, agg,
                                                    mw1, mb1, mw2, mb2, E);
        out_kernel<<<nodeBlocks, 256, 0, stream>>>(agg, l2w, l2b, lw, lb, outp, N);
    }
}

// Round 2
// 2040.433 us; speedup vs baseline: 3.0371x; 3.0371x over previous
//
#include <hip/hip_runtime.h>
#include <math.h>

#define HD 64   // H == F == 64
#define GD 50   // num gaussians

__device__ __forceinline__ float ssp_f(float x) {
    // shifted softplus: log1p(exp(x)) - ln(2)
    float sp = (x > 15.0f) ? x : log1pf(__expf(x));
    return sp - 0.69314718055994531f;
}

// xs = x @ l1w : [N,64]. One wave per node, lane = out col.
__global__ void __launch_bounds__(256) xs_kernel(const float* __restrict__ x,
                                                 const float* __restrict__ w,
                                                 float* __restrict__ xs, int N) {
    int wv = threadIdx.x >> 6;
    int j  = threadIdx.x & 63;
    int n  = blockIdx.x * 4 + wv;
    __shared__ float xr[4][64];
    if (n < N) xr[wv][j] = x[(size_t)n * HD + j];
    __syncthreads();
    if (n >= N) return;
    float acc = 0.0f;
#pragma unroll
    for (int k = 0; k < HD; ++k)
        acc = fmaf(xr[wv][k], w[k * HD + j], acc);
    xs[(size_t)n * HD + j] = acc;
}

// Per-edge: thread-per-edge filter MLP (weights via scalar loads), fold cosine
// cutoff, then LDS transpose (pad 65 -> conflict-free) so the gather+scatter
// runs in channel-space: per edge one coalesced 256B xs row read and ONE
// wave-coalesced atomic instruction (4 cache lines, vs 64 scattered before).
#define EPW 64                 // edges per wave
#define WPB 2                  // waves per block
__global__ void __launch_bounds__(WPB * 64) edge_kernel(
        const float* __restrict__ ea, const float* __restrict__ ew,
        const int* __restrict__ ei, const float* __restrict__ xs,
        float* __restrict__ agg,
        const float* __restrict__ mw1, const float* __restrict__ mb1,
        const float* __restrict__ mw2, const float* __restrict__ mb2,
        int E) {
    const int wv   = threadIdx.x >> 6;
    const int lane = threadIdx.x & 63;
    const long ebase = ((long)blockIdx.x * WPB + wv) * EPW;

    __shared__ float wbuf[WPB][EPW * 65];   // transposed filters, pad 65
    __shared__ int   sdst[WPB][EPW];
    __shared__ int   ssrc[WPB][EPW];

    long e = ebase + lane;
    bool valid = e < (long)E;
    long ec = valid ? e : (long)E - 1;      // clamp for safe loads

    // ---- filter MLP for edge ec (thread-private) ----
    const float2* ear2 = (const float2*)(ea + ec * GD);  // 200B rows, 8B aligned
    float a[GD];
#pragma unroll
    for (int g2 = 0; g2 < GD / 2; ++g2) {
        float2 v = ear2[g2];
        a[2 * g2]     = v.x;
        a[2 * g2 + 1] = v.y;
    }

    float h[HD];
#pragma unroll
    for (int f = 0; f < HD; ++f) h[f] = mb1[f];
#pragma unroll 5
    for (int g = 0; g < GD; ++g) {
        float ag = a[g];
        const float* wr = mw1 + g * HD;
#pragma unroll
        for (int f = 0; f < HD; ++f) h[f] = fmaf(ag, wr[f], h[f]);
    }

    float w[HD];
#pragma unroll
    for (int j = 0; j < HD; ++j) w[j] = mb2[j];
#pragma unroll 4
    for (int g = 0; g < HD; ++g) {
        float s = ssp_f(h[g]);
        const float* wr = mw2 + g * HD;
#pragma unroll
        for (int j = 0; j < HD; ++j) w[j] = fmaf(s, wr[j], w[j]);
    }

    // fold cosine cutoff; zero invalid edges so their atomic adds are no-ops
    float cw = 0.5f * (__cosf(ew[ec] * 0.31415926535897931f) + 1.0f);
    if (!valid) cw = 0.0f;

    // ---- transpose into LDS: row = my edge slot, col = channel ----
#pragma unroll
    for (int j = 0; j < HD; ++j)
        wbuf[wv][lane * 65 + j] = w[j] * cw;
    sdst[wv][lane] = ei[(size_t)E + ec];
    ssrc[wv][lane] = ei[ec];
    __syncthreads();

    // ---- channel-space gather + modulate + coalesced atomic scatter ----
#pragma unroll 4
    for (int t = 0; t < EPW; ++t) {
        int dst = sdst[wv][t];              // LDS broadcast (uniform)
        int src = ssrc[wv][t];
        float m = xs[(size_t)src * HD + lane] * wbuf[wv][t * 65 + lane];
        atomicAdd(&agg[(size_t)dst * HD + lane], m);
    }
}

// out = ssp(agg @ l2w + l2b) @ lin_w + lin_b. One wave per node, LDS broadcast.
__global__ void __launch_bounds__(256) out_kernel(
        const float* __restrict__ agg,
        const float* __restrict__ l2w, const float* __restrict__ l2b,
        const float* __restrict__ lw, const float* __restrict__ lb,
        float* __restrict__ out, int N) {
    int wv = threadIdx.x >> 6;
    int j  = threadIdx.x & 63;
    int n  = blockIdx.x * 4 + wv;
    __shared__ float buf[4][64];
    bool ok = n < N;
    if (ok) buf[wv][j] = agg[(size_t)n * HD + j];
    __syncthreads();
    float h = l2b[j];
#pragma unroll
    for (int g = 0; g < HD; ++g)
        h = fmaf(buf[wv][g], l2w[g * HD + j], h);
    h = ssp_f(h);
    __syncthreads();
    buf[wv][j] = h;
    __syncthreads();
    float o = lb[j];
#pragma unroll
    for (int g = 0; g < HD; ++g)
        o = fmaf(buf[wv][g], lw[g * HD + j], o);
    if (ok) out[(size_t)n * HD + j] = o;
}

extern "C" void kernel_launch(void* const* d_in, const int* in_sizes, int n_in,
                              void* d_out, int out_size, void* d_ws, size_t ws_size,
                              hipStream_t stream) {
    const float* x0   = (const float*)d_in[0];
    const float* x1   = (const float*)d_in[1];
    const int*   ei0  = (const int*)d_in[2];
    const int*   ei1  = (const int*)d_in[3];
    const float* ew0  = (const float*)d_in[4];
    const float* ew1  = (const float*)d_in[5];
    const float* ea0  = (const float*)d_in[6];
    const float* ea1  = (const float*)d_in[7];
    const float* mw1  = (const float*)d_in[8];
    const float* mb1  = (const float*)d_in[9];
    const float* mw2  = (const float*)d_in[10];
    const float* mb2  = (const float*)d_in[11];
    const float* l1w0 = (const float*)d_in[12];
    const float* l2w0 = (const float*)d_in[13];
    const float* l2b0 = (const float*)d_in[14];
    const float* l1w1 = (const float*)d_in[15];
    const float* l2w1 = (const float*)d_in[16];
    const float* l2b1 = (const float*)d_in[17];
    const float* lw   = (const float*)d_in[18];
    const float* lb   = (const float*)d_in[19];

    int N = in_sizes[0] / HD;
    int E = in_sizes[4];
    float* out = (float*)d_out;

    float* xs  = (float*)d_ws;
    float* agg = xs + (size_t)N * HD;

    int nodeBlocks = (N + 3) / 4;
    int edgeBlocks = (E + WPB * EPW - 1) / (WPB * EPW);

    for (int t = 0; t < 2; ++t) {
        const float* x   = t ? x1 : x0;
        const int*   ei  = t ? ei1 : ei0;
        const float* ew  = t ? ew1 : ew0;
        const float* ea  = t ? ea1 : ea0;
        const float* l1w = t ? l1w1 : l1w0;
        const float* l2w = t ? l2w1 : l2w0;
        const float* l2b = t ? l2b1 : l2b0;
        float* outp = out + (size_t)t * (size_t)N * HD;

        xs_kernel<<<nodeBlocks, 256, 0, stream>>>(x, l1w, xs, N);
        hipMemsetAsync(agg, 0, (size_t)N * HD * sizeof(float), stream);
        edge_kernel<<<edgeBlocks, WPB * 64, 0, stream>>>(ea, ew, ei, xs, agg,
                                                         mw1, mb1, mw2, mb2, E);
        out_kernel<<<nodeBlocks, 256, 0, stream>>>(agg, l2w, l2b, lw, lb, outp, N);
    }
}

// Round 3
// 1538.172 us; speedup vs baseline: 4.0287x; 1.3265x over previous
//
#include <hip/hip_runtime.h>
#include <math.h>

#define HD 64   // H == F == 64
#define GD 50   // num gaussians

__device__ __forceinline__ float ssp_f(float x) {
    // shifted softplus: softplus(x) - ln2, stable form max(x,0)+log(1+exp(-|x|))
    float ax = __builtin_fabsf(x);
    float e  = __expf(-ax);
    float sp = fmaxf(x, 0.0f) + __logf(1.0f + e);
    return sp - 0.69314718055994531f;
}

// xs = x @ l1w : [N,64]. One wave per node, lane = out col.
__global__ void __launch_bounds__(256) xs_kernel(const float* __restrict__ x,
                                                 const float* __restrict__ w,
                                                 float* __restrict__ xs, int N) {
    int wv = threadIdx.x >> 6;
    int j  = threadIdx.x & 63;
    int n  = blockIdx.x * 4 + wv;
    __shared__ float xr[4][64];
    if (n < N) xr[wv][j] = x[(size_t)n * HD + j];
    __syncthreads();
    if (n >= N) return;
    float acc = 0.0f;
#pragma unroll
    for (int k = 0; k < HD; ++k)
        acc = fmaf(xr[wv][k], w[k * HD + j], acc);
    xs[(size_t)n * HD + j] = acc;
}

// Per-edge: thread-per-edge filter MLP (weights via scalar loads, h/w fully in
// VGPRs -- launch_bounds(,2) allows 256 VGPR so nothing spills), fold cosine
// cutoff, LDS transpose (pad 65), then channel-space gather + one
// wave-coalesced atomic per edge.
#define EPW 64                 // edges per wave
#define WPB 2                  // waves per block
__global__ void __launch_bounds__(WPB * 64, 2) edge_kernel(
        const float* __restrict__ ea, const float* __restrict__ ew,
        const int* __restrict__ ei, const float* __restrict__ xs,
        float* __restrict__ agg,
        const float* __restrict__ mw1, const float* __restrict__ mb1,
        const float* __restrict__ mw2, const float* __restrict__ mb2,
        int E) {
    const int wv   = threadIdx.x >> 6;
    const int lane = threadIdx.x & 63;
    const long ebase = ((long)blockIdx.x * WPB + wv) * EPW;

    __shared__ float wbuf[WPB][EPW * 65];   // transposed filters, pad 65
    __shared__ int   sdst[WPB][EPW];
    __shared__ int   ssrc[WPB][EPW];

    long e = ebase + lane;
    bool valid = e < (long)E;
    long ec = valid ? e : (long)E - 1;      // clamp for safe loads

    // ---- layer 1: h = ea_row @ mw1 + mb1 (stream ea as float2 chunks) ----
    const float2* ear2 = (const float2*)(ea + ec * GD);  // 200B rows, 8B aligned
    float h[HD];
#pragma unroll
    for (int f = 0; f < HD; ++f) h[f] = mb1[f];
    for (int gc = 0; gc < GD / 2; ++gc) {   // 25 iters, body ~128 FMA
        float2 v = ear2[gc];
        const float* wr = mw1 + 2 * gc * HD;
#pragma unroll
        for (int f = 0; f < HD; ++f) h[f] = fmaf(v.x, wr[f], h[f]);
#pragma unroll
        for (int f = 0; f < HD; ++f) h[f] = fmaf(v.y, wr[HD + f], h[f]);
    }

    // ---- layer 2: w = ssp(h) @ mw2 + mb2 ----
    float w[HD];
#pragma unroll
    for (int j = 0; j < HD; ++j) w[j] = mb2[j];
    for (int g = 0; g < HD; ++g) {          // 64 iters, body = ssp + 64 FMA
        float s = ssp_f(h[g]);
        const float* wr = mw2 + g * HD;
#pragma unroll
        for (int j = 0; j < HD; ++j) w[j] = fmaf(s, wr[j], w[j]);
    }

    // fold cosine cutoff; zero invalid edges so their atomic adds are no-ops
    float cw = 0.5f * (__cosf(ew[ec] * 0.31415926535897931f) + 1.0f);
    if (!valid) cw = 0.0f;

    // ---- transpose into LDS: row = my edge slot, col = channel ----
#pragma unroll
    for (int j = 0; j < HD; ++j)
        wbuf[wv][lane * 65 + j] = w[j] * cw;
    sdst[wv][lane] = ei[(size_t)E + ec];
    ssrc[wv][lane] = ei[ec];
    __syncthreads();

    // ---- channel-space gather + modulate + coalesced atomic scatter ----
#pragma unroll 8
    for (int t = 0; t < EPW; ++t) {
        int dst = sdst[wv][t];              // LDS broadcast (uniform)
        int src = ssrc[wv][t];
        float m = xs[(size_t)src * HD + lane] * wbuf[wv][t * 65 + lane];
        atomicAdd(&agg[(size_t)dst * HD + lane], m);
    }
}

// out = ssp(agg @ l2w + l2b) @ lin_w + lin_b. One wave per node, LDS broadcast.
__global__ void __launch_bounds__(256) out_kernel(
        const float* __restrict__ agg,
        const float* __restrict__ l2w, const float* __restrict__ l2b,
        const float* __restrict__ lw, const float* __restrict__ lb,
        float* __restrict__ out, int N) {
    int wv = threadIdx.x >> 6;
    int j  = threadIdx.x & 63;
    int n  = blockIdx.x * 4 + wv;
    __shared__ float buf[4][64];
    bool ok = n < N;
    if (ok) buf[wv][j] = agg[(size_t)n * HD + j];
    __syncthreads();
    float h = l2b[j];
#pragma unroll
    for (int g = 0; g < HD; ++g)
        h = fmaf(buf[wv][g], l2w[g * HD + j], h);
    h = ssp_f(h);
    __syncthreads();
    buf[wv][j] = h;
    __syncthreads();
    float o = lb[j];
#pragma unroll
    for (int g = 0; g < HD; ++g)
        o = fmaf(buf[wv][g], lw[g * HD + j], o);
    if (ok) out[(size_t)n * HD + j] = o;
}

extern "C" void kernel_launch(void* const* d_in, const int* in_sizes, int n_in,
                              void* d_out, int out_size, void* d_ws, size_t ws_size,
                              hipStream_t stream) {
    const float* x0   = (const float*)d_in[0];
    const float* x1   = (const float*)d_in[1];
    const int*   ei0  = (const int*)d_in[2];
    const int*   ei1  = (const int*)d_in[3];
    const float* ew0  = (const float*)d_in[4];
    const float* ew1  = (const float*)d_in[5];
    const float* ea0  = (const float*)d_in[6];
    const float* ea1  = (const float*)d_in[7];
    const float* mw1  = (const float*)d_in[8];
    const float* mb1  = (const float*)d_in[9];
    const float* mw2  = (const float*)d_in[10];
    const float* mb2  = (const float*)d_in[11];
    const float* l1w0 = (const float*)d_in[12];
    const float* l2w0 = (const float*)d_in[13];
    const float* l2b0 = (const float*)d_in[14];
    const float* l1w1 = (const float*)d_in[15];
    const float* l2w1 = (const float*)d_in[16];
    const float* l2b1 = (const float*)d_in[17];
    const float* lw   = (const float*)d_in[18];
    const float* lb   = (const float*)d_in[19];

    int N = in_sizes[0] / HD;
    int E = in_sizes[4];
    float* out = (float*)d_out;

    float* xs  = (float*)d_ws;
    float* agg = xs + (size_t)N * HD;

    int nodeBlocks = (N + 3) / 4;
    int edgeBlocks = (E + WPB * EPW - 1) / (WPB * EPW);

    for (int t = 0; t < 2; ++t) {
        const float* x   = t ? x1 : x0;
        const int*   ei  = t ? ei1 : ei0;
        const float* ew  = t ? ew1 : ew0;
        const float* ea  = t ? ea1 : ea0;
        const float* l1w = t ? l1w1 : l1w0;
        const float* l2w = t ? l2w1 : l2w0;
        const float* l2b = t ? l2b1 : l2b0;
        float* outp = out + (size_t)t * (size_t)N * HD;

        xs_kernel<<<nodeBlocks, 256, 0, stream>>>(x, l1w, xs, N);
        hipMemsetAsync(agg, 0, (size_t)N * HD * sizeof(float), stream);
        edge_kernel<<<edgeBlocks, WPB * 64, 0, stream>>>(ea, ew, ei, xs, agg,
                                                         mw1, mb1, mw2, mb2, E);
        out_kernel<<<nodeBlocks, 256, 0, stream>>>(agg, l2w, l2b, lw, lb, outp, N);
    }
}

// Round 4
// 1433.452 us; speedup vs baseline: 4.3231x; 1.0731x over previous
//
#include <hip/hip_runtime.h>
#include <math.h>

#define HD 64   // H == F == 64
#define GD 50   // num gaussians
#define PAD 68  // LDS row stride in floats: 272B, 16B-aligned, b128-conflict-free

__device__ __forceinline__ float ssp_f(float x) {
    // shifted softplus: softplus(x) - ln2, stable form max(x,0)+log(1+exp(-|x|))
    float ax = __builtin_fabsf(x);
    float e  = __expf(-ax);
    float sp = fmaxf(x, 0.0f) + __logf(1.0f + e);
    return sp - 0.69314718055994531f;
}

// xs = x @ l1w : [N,64]; also zero agg (saves separate memset dispatches).
__global__ void __launch_bounds__(256) xs_kernel(const float* __restrict__ x,
                                                 const float* __restrict__ w,
                                                 float* __restrict__ xs,
                                                 float* __restrict__ agg, int N) {
    int wv = threadIdx.x >> 6;
    int j  = threadIdx.x & 63;
    int n  = blockIdx.x * 4 + wv;
    __shared__ float xr[4][64];
    if (n < N) xr[wv][j] = x[(size_t)n * HD + j];
    __syncthreads();
    if (n >= N) return;
    float acc = 0.0f;
#pragma unroll
    for (int k = 0; k < HD; ++k)
        acc = fmaf(xr[wv][k], w[k * HD + j], acc);
    xs[(size_t)n * HD + j] = acc;
    agg[(size_t)n * HD + j] = 0.0f;
}

// Per-edge filter MLP + modulate + scatter.
//   Layer 1: h accumulated in VGPRs (static idx), weights scalar-loaded.
//   h parked in LDS (row lane, stride PAD) -> layer 2 reads h[g] via
//   ds_read_b128 blocks (no scratch, no dynamic VGPR indexing).
//   w[64] register-resident; overwrites the same LDS row (transposed store).
//   Scatter: channel-space, one wave-coalesced atomic per edge (4 lines).
#define EPW 64
#define WPB 2
__global__ void __launch_bounds__(WPB * 64, 2) edge_kernel(
        const float* __restrict__ ea, const float* __restrict__ ew,
        const int* __restrict__ ei, const float* __restrict__ xs,
        float* __restrict__ agg,
        const float* __restrict__ mw1, const float* __restrict__ mb1,
        const float* __restrict__ mw2, const float* __restrict__ mb2,
        int E) {
    const int wv   = threadIdx.x >> 6;
    const int lane = threadIdx.x & 63;
    const long ebase = ((long)blockIdx.x * WPB + wv) * EPW;

    __shared__ float wbuf[WPB][EPW * PAD];  // holds h, then w*cw (same slot)
    __shared__ int   sdst[WPB][EPW];
    __shared__ int   ssrc[WPB][EPW];

    long e = ebase + lane;
    bool valid = e < (long)E;
    long ec = valid ? e : (long)E - 1;

    // ---- layer 1: h = ea_row @ mw1 + mb1 (h static-indexed -> VGPRs) ----
    const float2* ear2 = (const float2*)(ea + ec * GD);
    float h[HD];
#pragma unroll
    for (int f = 0; f < HD; ++f) h[f] = mb1[f];
    for (int gc = 0; gc < GD / 2; ++gc) {       // 25 iters, uniform weight rows
        float2 v = ear2[gc];
        const float* wr = mw1 + 2 * gc * HD;
#pragma unroll
        for (int f = 0; f < HD; ++f) h[f] = fmaf(v.x, wr[f], h[f]);
#pragma unroll
        for (int f = 0; f < HD; ++f) h[f] = fmaf(v.y, wr[HD + f], h[f]);
    }

    // ---- park h in LDS (own row, b128 stores, conflict-free) ----
    float* hrow = &wbuf[wv][lane * PAD];
#pragma unroll
    for (int q = 0; q < HD / 4; ++q)
        *(float4*)(hrow + 4 * q) = make_float4(h[4*q], h[4*q+1], h[4*q+2], h[4*q+3]);

    // ---- layer 2: w = ssp(h) @ mw2 + mb2 (w static-indexed -> VGPRs) ----
    float w[HD];
#pragma unroll
    for (int j = 0; j < HD; ++j) w[j] = mb2[j];
    for (int gb = 0; gb < HD / 4; ++gb) {       // 16 iters: b128 read + 4x64 FMA
        float4 hv = *(const float4*)(hrow + 4 * gb);
        float s0 = ssp_f(hv.x), s1 = ssp_f(hv.y), s2 = ssp_f(hv.z), s3 = ssp_f(hv.w);
        const float* wr = mw2 + 4 * gb * HD;
#pragma unroll
        for (int j = 0; j < HD; ++j) w[j] = fmaf(s0, wr[j], w[j]);
#pragma unroll
        for (int j = 0; j < HD; ++j) w[j] = fmaf(s1, wr[HD + j], w[j]);
#pragma unroll
        for (int j = 0; j < HD; ++j) w[j] = fmaf(s2, wr[2 * HD + j], w[j]);
#pragma unroll
        for (int j = 0; j < HD; ++j) w[j] = fmaf(s3, wr[3 * HD + j], w[j]);
    }

    // fold cosine cutoff; zero invalid edges so their atomics are no-ops
    float cw = 0.5f * (__cosf(ew[ec] * 0.31415926535897931f) + 1.0f);
    if (!valid) cw = 0.0f;

    // ---- overwrite own LDS row with w*cw (transposed store) ----
#pragma unroll
    for (int q = 0; q < HD / 4; ++q)
        *(float4*)(hrow + 4 * q) = make_float4(w[4*q] * cw, w[4*q+1] * cw,
                                               w[4*q+2] * cw, w[4*q+3] * cw);
    sdst[wv][lane] = ei[(size_t)E + ec];
    ssrc[wv][lane] = ei[ec];
    __syncthreads();   // LDS fence insurance before column-wise reads

    // ---- channel-space gather + modulate + coalesced atomic scatter ----
#pragma unroll 8
    for (int t = 0; t < EPW; ++t) {
        int dst = sdst[wv][t];
        int src = ssrc[wv][t];
        float m = xs[(size_t)src * HD + lane] * wbuf[wv][t * PAD + lane];
        atomicAdd(&agg[(size_t)dst * HD + lane], m);
    }
}

// out = ssp(agg @ l2w + l2b) @ lin_w + lin_b. One wave per node, LDS broadcast.
__global__ void __launch_bounds__(256) out_kernel(
        const float* __restrict__ agg,
        const float* __restrict__ l2w, const float* __restrict__ l2b,
        const float* __restrict__ lw, const float* __restrict__ lb,
        float* __restrict__ out, int N) {
    int wv = threadIdx.x >> 6;
    int j  = threadIdx.x & 63;
    int n  = blockIdx.x * 4 + wv;
    __shared__ float buf[4][64];
    bool ok = n < N;
    if (ok) buf[wv][j] = agg[(size_t)n * HD + j];
    __syncthreads();
    float h = l2b[j];
#pragma unroll
    for (int g = 0; g < HD; ++g)
        h = fmaf(buf[wv][g], l2w[g * HD + j], h);
    h = ssp_f(h);
    __syncthreads();
    buf[wv][j] = h;
    __syncthreads();
    float o = lb[j];
#pragma unroll
    for (int g = 0; g < HD; ++g)
        o = fmaf(buf[wv][g], lw[g * HD + j], o);
    if (ok) out[(size_t)n * HD + j] = o;
}

extern "C" void kernel_launch(void* const* d_in, const int* in_sizes, int n_in,
                              void* d_out, int out_size, void* d_ws, size_t ws_size,
                              hipStream_t stream) {
    const float* x0   = (const float*)d_in[0];
    const float* x1   = (const float*)d_in[1];
    const int*   ei0  = (const int*)d_in[2];
    const int*   ei1  = (const int*)d_in[3];
    const float* ew0  = (const float*)d_in[4];
    const float* ew1  = (const float*)d_in[5];
    const float* ea0  = (const float*)d_in[6];
    const float* ea1  = (const float*)d_in[7];
    const float* mw1  = (const float*)d_in[8];
    const float* mb1  = (const float*)d_in[9];
    const float* mw2  = (const float*)d_in[10];
    const float* mb2  = (const float*)d_in[11];
    const float* l1w0 = (const float*)d_in[12];
    const float* l2w0 = (const float*)d_in[13];
    const float* l2b0 = (const float*)d_in[14];
    const float* l1w1 = (const float*)d_in[15];
    const float* l2w1 = (const float*)d_in[16];
    const float* l2b1 = (const float*)d_in[17];
    const float* lw   = (const float*)d_in[18];
    const float* lb   = (const float*)d_in[19];

    int N = in_sizes[0] / HD;
    int E = in_sizes[4];
    float* out = (float*)d_out;

    float* xs  = (float*)d_ws;
    float* agg = xs + (size_t)N * HD;

    int nodeBlocks = (N + 3) / 4;
    int edgeBlocks = (E + WPB * EPW - 1) / (WPB * EPW);

    for (int t = 0; t < 2; ++t) {
        const float* x   = t ? x1 : x0;
        const int*   ei  = t ? ei1 : ei0;
        const float* ew  = t ? ew1 : ew0;
        const float* ea  = t ? ea1 : ea0;
        const float* l1w = t ? l1w1 : l1w0;
        const float* l2w = t ? l2w1 : l2w0;
        const float* l2b = t ? l2b1 : l2b0;
        float* outp = out + (size_t)t * (size_t)N * HD;

        xs_kernel<<<nodeBlocks, 256, 0, stream>>>(x, l1w, xs, agg, N);
        edge_kernel<<<edgeBlocks, WPB * 64, 0, stream>>>(ea, ew, ei, xs, agg,
                                                         mw1, mb1, mw2, mb2, E);
        out_kernel<<<nodeBlocks, 256, 0, stream>>>(agg, l2w, l2b, lw, lb, outp, N);
    }
}